// Round 17
// baseline (116.846 us; speedup 1.0000x reference)
//
#include <hip/hip_runtime.h>

// All tensors float32. Math structure exploited:
//  - softmax over axis of size 1 == 1.0 -> attn all-ones, Wa/ba dead.
//  - weighted = row-sum of tanh(agg), broadcast over COLUMNS (N==D quirk).
//  - lig_p = nf@Wl.T + const  ->  x0[h,i,j] = PL[i,h] + PR[j,h] + c[h]
//  - conv1 is LINEAR in rank-structured x0: y1_pre = U[xc][y] + V[yc][x] + K'.
//  - ROUND-17: conv was LDS-READ-ISSUE-BOUND (54 ds_read_b128/lane/tile ->
//    83K cyc/CU = 35us floor). New conv: persistent blocks (8 tiles each,
//    grid 512), Bf hoisted to VGPRs once per block (18 B-reads/lane/block),
//    u-octs shared across the block's row of tiles, v prefetched under MFMA,
//    ys double-buffered with ONE barrier per tile, oct(half8) staging.
//    New LDS floor ~13us/CU. pp: Ws staging loop unrolled (zero risk).

typedef _Float16 half8 __attribute__((ext_vector_type(8)));
typedef _Float16 half4 __attribute__((ext_vector_type(4)));
typedef float    f32x4 __attribute__((ext_vector_type(4)));

__device__ __forceinline__ short f2h_bits(float f){
    _Float16 h = (_Float16)f;          // RNE
    return __builtin_bit_cast(short, h);
}
__device__ __forceinline__ half8 pack2(const float4& x, const float4& y){
    half8 r;
    r[0] = (_Float16)x.x; r[1] = (_Float16)x.y;
    r[2] = (_Float16)x.z; r[3] = (_Float16)x.w;
    r[4] = (_Float16)y.x; r[5] = (_Float16)y.y;
    r[6] = (_Float16)y.z; r[7] = (_Float16)y.w;
    return r;
}
__device__ __forceinline__ half4 pack4(const float4& x){
    half4 r;
    r[0] = (_Float16)x.x; r[1] = (_Float16)x.y;
    r[2] = (_Float16)x.z; r[3] = (_Float16)x.w;
    return r;
}
__device__ __forceinline__ float tanh_fast(float x){
    float e = __expf(2.f * x);
    return 1.f - 2.f / (e + 1.f);
}

// ci-block swizzle for conv LDS tiles (round-4 verified layout)
#define SWZ(c) ((((c) >> 1) & 3) << 3)

// ---------------------------------------------------------------------------
// K1 (MFMA): gnn, BM=128/BN=64/BK=64, 512 thr, depth-2 reg prefetch.
// grid (8,16,2). (round-15/16 verbatim)
// ---------------------------------------------------------------------------
#define GNN_LOAD(AV, BV, KBN) {                                              \
    const int kbn_ = (KBN) & 2047;                                           \
    const float* Asrc_ = (kbn_ < 1024) ? A0 : A1;                            \
    const float* Bsrc_ = (kbn_ < 1024) ? Wn : We;                            \
    const int kk_ = kbn_ & 1023;                                             \
    const float* ap_ = Asrc_ + (size_t)(j0 + arow) * 1024 + kk_ + akc;       \
    const float* bp_ = Bsrc_ + (size_t)(d0 + brow) * 1024 + kk_ + bkc;       \
    AV[0] = *reinterpret_cast<const float4*>(ap_);                           \
    AV[1] = *reinterpret_cast<const float4*>(ap_ + 4);                       \
    AV[2] = *reinterpret_cast<const float4*>(ap_ + 8);                       \
    AV[3] = *reinterpret_cast<const float4*>(ap_ + 12);                      \
    BV[0] = *reinterpret_cast<const float4*>(bp_);                           \
    BV[1] = *reinterpret_cast<const float4*>(bp_ + 4);                       \
}

#define GNN_STAGE(AV, BV) {                                                  \
    const int ga_ = (t & 3) * 2;                                             \
    const int sa_ = arow & 7;                                                \
    *reinterpret_cast<half8*>(&As[arow * 64 + ((ga_    ) ^ sa_) * 8]) = pack2(AV[0], AV[1]); \
    *reinterpret_cast<half8*>(&As[arow * 64 + ((ga_ + 1) ^ sa_) * 8]) = pack2(AV[2], AV[3]); \
    *reinterpret_cast<half8*>(&Bs[brow * 64 + ((t & 7) ^ (brow & 7)) * 8]) = pack2(BV[0], BV[1]); \
}

#define GNN_MFMA() {                                                         \
    _Pragma("unroll")                                                        \
    for (int ks = 0; ks < 2; ++ks){                                          \
        half8 Af[2], Bf[2];                                                  \
        _Pragma("unroll")                                                    \
        for (int m = 0; m < 2; ++m){                                         \
            int row = wm * 32 + m * 16 + lr;                                 \
            int g   = ((ks * 4 + lg) ^ (row & 7)) * 8;                       \
            Af[m] = *reinterpret_cast<const half8*>(&As[row * 64 + g]);      \
        }                                                                    \
        _Pragma("unroll")                                                    \
        for (int n = 0; n < 2; ++n){                                         \
            int col = wn * 32 + n * 16 + lr;                                 \
            int g   = ((ks * 4 + lg) ^ (col & 7)) * 8;                       \
            Bf[n] = *reinterpret_cast<const half8*>(&Bs[col * 64 + g]);      \
        }                                                                    \
        _Pragma("unroll")                                                    \
        for (int m = 0; m < 2; ++m)                                          \
            _Pragma("unroll")                                                \
            for (int n = 0; n < 2; ++n)                                      \
                acc[m][n] = __builtin_amdgcn_mfma_f32_16x16x32_f16(          \
                    Af[m], Bf[n], acc[m][n], 0, 0, 0);                       \
    }                                                                        \
}

__global__ __launch_bounds__(512) void gnn_kernel(
    const float* __restrict__ lig_nf, const float* __restrict__ lig_ef,
    const float* __restrict__ rec_nf, const float* __restrict__ rec_ef,
    const float* __restrict__ Wn, const float* __restrict__ We,
    const float* __restrict__ bn, const float* __restrict__ be,
    float* __restrict__ part)   // [2][16][1024]
{
    __shared__ __attribute__((aligned(16))) short As[128 * 64];
    __shared__ __attribute__((aligned(16))) short Bs[64 * 64];
    __shared__ float red[128][2];

    const int t  = threadIdx.x;
    const int cx = blockIdx.z;
    const float* A0 = cx ? rec_nf : lig_nf;
    const float* A1 = cx ? rec_ef : lig_ef;
    const int j0 = blockIdx.x * 128;
    const int d0 = blockIdx.y * 64;

    const int wid  = t >> 6;
    const int wm   = wid >> 1;
    const int wn   = wid & 1;
    const int lane = t & 63;
    const int lr   = lane & 15;
    const int lg   = lane >> 4;

    f32x4 acc[2][2];
    #pragma unroll
    for (int m = 0; m < 2; ++m)
        #pragma unroll
        for (int n = 0; n < 2; ++n)
            acc[m][n] = (f32x4){0.f, 0.f, 0.f, 0.f};

    const int arow = t >> 2;
    const int akc  = (t & 3) * 16;
    const int brow = t >> 3;
    const int bkc  = (t & 7) * 8;

    float4 avA[4], bvA[2], avB[4], bvB[2];
    GNN_LOAD(avA, bvA, 0);
    GNN_LOAD(avB, bvB, 64);

    for (int kb = 0; kb < 2048; kb += 128){
        __syncthreads();
        GNN_STAGE(avA, bvA);
        GNN_LOAD(avA, bvA, kb + 128);
        __syncthreads();
        GNN_MFMA();
        __syncthreads();
        GNN_STAGE(avB, bvB);
        GNN_LOAD(avB, bvB, kb + 192);
        __syncthreads();
        GNN_MFMA();
    }

    float rowsum[2][4];
    #pragma unroll
    for (int m = 0; m < 2; ++m)
        #pragma unroll
        for (int jj = 0; jj < 4; ++jj) rowsum[m][jj] = 0.f;
    #pragma unroll
    for (int n = 0; n < 2; ++n){
        int d = d0 + wn * 32 + n * 16 + lr;
        float bias = bn[d] + be[d];
        #pragma unroll
        for (int m = 0; m < 2; ++m)
            #pragma unroll
            for (int jj = 0; jj < 4; ++jj)
                rowsum[m][jj] += tanh_fast(acc[m][n][jj] + bias);
    }
    #pragma unroll
    for (int mask = 1; mask < 16; mask <<= 1)
        #pragma unroll
        for (int m = 0; m < 2; ++m)
            #pragma unroll
            for (int jj = 0; jj < 4; ++jj)
                rowsum[m][jj] += __shfl_xor(rowsum[m][jj], mask);
    __syncthreads();
    if (lr == 0){
        #pragma unroll
        for (int m = 0; m < 2; ++m)
            #pragma unroll
            for (int jj = 0; jj < 4; ++jj)
                red[wm * 32 + m * 16 + lg * 4 + jj][wn] = rowsum[m][jj];
    }
    __syncthreads();
    if (t < 128)
        part[(size_t)cx * 16384 + (size_t)blockIdx.y * 1024 + j0 + t]
            = red[t][0] + red[t][1];
}

// ---------------------------------------------------------------------------
// K2: pp_kernel. grid 34 x 512 thr. (round-16 + unrolled Ws staging)
// ---------------------------------------------------------------------------
#define PP_LOAD(AV, BV, KBN) {                                               \
    const int kcol_ = (KBN) & 1023;                                          \
    _Pragma("unroll")                                                        \
    for (int p = 0; p < 3; ++p){                                             \
        int e_ = t + 512 * p;                                                \
        if (e_ < 1280){                                                      \
            int rowl_ = e_ >> 4;                                             \
            int grow_ = r0 - 8 + rowl_;                                      \
            if ((unsigned)grow_ < 1024u)                                     \
                AV[p] = *reinterpret_cast<const float4*>(                    \
                    nf + (size_t)grow_ * 1024 + kcol_ + (e_ & 15) * 4);      \
            else                                                             \
                AV[p] = make_float4(0.f, 0.f, 0.f, 0.f);                     \
        }                                                                    \
    }                                                                        \
    BV = *reinterpret_cast<const float4*>(                                   \
        W + (size_t)(t >> 4) * 2048 + kcol_ + (t & 15) * 4);                 \
}

#define PP_STAGE(AV, BV) {                                                   \
    _Pragma("unroll")                                                        \
    for (int p = 0; p < 3; ++p){                                             \
        int e_ = t + 512 * p;                                                \
        if (e_ < 1280){                                                      \
            int rowl_ = e_ >> 4;                                             \
            int ga_ = (e_ & 15) >> 1;                                        \
            int sub_ = (e_ & 1) * 4;                                         \
            *reinterpret_cast<half4*>(                                       \
                &As[rowl_ * 64 + ((ga_ ^ (rowl_ & 7)) * 8) + sub_]) = pack4(AV[p]); \
        }                                                                    \
    }                                                                        \
    {                                                                        \
        int row_ = t >> 4;                                                   \
        int ga_ = (t & 15) >> 1;                                             \
        int sub_ = (t & 1) * 4;                                              \
        *reinterpret_cast<half4*>(                                           \
            &Bs[row_ * 64 + ((ga_ ^ (row_ & 7)) * 8) + sub_]) = pack4(BV);   \
    }                                                                        \
}

#define PP_MFMA() {                                                          \
    if (wid < 5){                                                            \
        _Pragma("unroll")                                                    \
        for (int ks = 0; ks < 2; ++ks){                                      \
            int ar_ = wid * 16 + lr;                                         \
            half8 Af = *reinterpret_cast<const half8*>(                      \
                &As[ar_ * 64 + ((ks * 4 + lg) ^ (ar_ & 7)) * 8]);            \
            _Pragma("unroll")                                                \
            for (int n = 0; n < 2; ++n){                                     \
                int col_ = n * 16 + lr;                                      \
                half8 Bf = *reinterpret_cast<const half8*>(                  \
                    &Bs[col_ * 64 + ((ks * 4 + lg) ^ (col_ & 7)) * 8]);      \
                pacc[n] = __builtin_amdgcn_mfma_f32_16x16x32_f16(            \
                    Af, Bf, pacc[n], 0, 0, 0);                               \
            }                                                                \
        }                                                                    \
    }                                                                        \
}

__global__ __launch_bounds__(512) void pp_kernel(
    const float* __restrict__ lig_nf, const float* __restrict__ rec_nf,
    const float* __restrict__ W_hopi, const float* __restrict__ b_hopi,
    const float* __restrict__ w1, const float* __restrict__ b1,
    const float* __restrict__ w2,
    const float* __restrict__ part,
    float* __restrict__ Kp, short* __restrict__ U16, short* __restrict__ V16,
    short* __restrict__ w2f16)
{
    __shared__ __attribute__((aligned(16))) char smem[47232];
    const int t = threadIdx.x;
    const int role = blockIdx.x;

    if (role < 32){
        short* As = reinterpret_cast<short*>(smem);            // 80x64  @0
        short* Bs = reinterpret_cast<short*>(smem + 10240);    // 32x64
        short* Pz = reinterpret_cast<short*>(smem + 14336);    // 80 x stride40
        short* Ws = reinterpret_cast<short*>(smem + 20736);    // 3x32 x stride104

        const int cx = role >> 4;
        const int r0 = (role & 15) * 64;
        const float* nf = cx ? rec_nf : lig_nf;
        const float* W  = W_hopi + (cx ? 1024 : 0);
        short* O = cx ? V16 : U16;

        const int wid = t >> 6;
        const int lane = t & 63;
        const int lr = lane & 15;
        const int lg = lane >> 4;

        // ---- stage Ws[cs][co][k=d*32+ci] (stride 104), unrolled ----
        #pragma unroll
        for (int q = 0; q < 18; ++q){
            int e = t + q * 512;
            int cs  = e / 3072;
            int rem = e - cs * 3072;
            int co  = rem / 96;
            int k   = rem - co * 96;
            int d   = k >> 5;
            int ci  = k & 31;
            int o_lo = (cs == 1) ? 1 : 0;
            int o_hi = (cs == 2) ? 1 : 2;
            float s = 0.f;
            for (int o = o_lo; o <= o_hi; ++o){
                int tap = cx ? (o * 3 + d) : (d * 3 + o);
                s += w1[co * 288 + ci * 9 + tap];
            }
            Ws[(cs * 32 + co) * 104 + k] = f2h_bits(s);
        }

        // ---- P GEMM: 80 rows x 32 h, K=1024, depth-2 prefetch ----
        f32x4 pacc[2];
        pacc[0] = (f32x4){0.f, 0.f, 0.f, 0.f};
        pacc[1] = (f32x4){0.f, 0.f, 0.f, 0.f};

        float4 avA[3], avB[3];
        float4 bvA, bvB;
        PP_LOAD(avA, bvA, 0);
        PP_LOAD(avB, bvB, 64);

        for (int kb = 0; kb < 1024; kb += 128){
            __syncthreads();
            PP_STAGE(avA, bvA);
            PP_LOAD(avA, bvA, kb + 128);
            __syncthreads();
            PP_MFMA();
            __syncthreads();
            PP_STAGE(avB, bvB);
            PP_LOAD(avB, bvB, kb + 192);
            __syncthreads();
            PP_MFMA();
        }

        if (wid < 5){
            #pragma unroll
            for (int n = 0; n < 2; ++n)
                #pragma unroll
                for (int jj = 0; jj < 4; ++jj){
                    int rowl = wid * 16 + lg * 4 + jj;
                    Pz[rowl * 40 + n * 16 + lr] = f2h_bits(pacc[n][jj]);
                }
        }
        __syncthreads();

        if (wid < 4){
            f32x4 uacc[3][2];
            #pragma unroll
            for (int cs = 0; cs < 3; ++cs)
                #pragma unroll
                for (int n = 0; n < 2; ++n)
                    uacc[cs][n] = (f32x4){0.f, 0.f, 0.f, 0.f};
            #pragma unroll
            for (int d = 0; d < 3; ++d){
                int ar = wid * 16 + lr;
                half8 Ap = *reinterpret_cast<const half8*>(
                    &Pz[(7 + ar + d) * 40 + lg * 8]);
                #pragma unroll
                for (int cs = 0; cs < 3; ++cs)
                    #pragma unroll
                    for (int n = 0; n < 2; ++n){
                        half8 Bp = *reinterpret_cast<const half8*>(
                            &Ws[(cs * 32 + n * 16 + lr) * 104 + d * 32 + lg * 8]);
                        uacc[cs][n] = __builtin_amdgcn_mfma_f32_16x16x32_f16(
                            Ap, Bp, uacc[cs][n], 0, 0, 0);
                    }
            }
            #pragma unroll
            for (int cs = 0; cs < 3; ++cs)
                #pragma unroll
                for (int n = 0; n < 2; ++n)
                    #pragma unroll
                    for (int jj = 0; jj < 4; ++jj){
                        int grow = r0 + wid * 16 + lg * 4 + jj;
                        O[((size_t)(cs << 10) + grow) * 32 + n * 16 + lr]
                            = f2h_bits(uacc[cs][n][jj]);
                    }
        }
        return;
    }

    if (role == 33){
        #pragma unroll
        for (int q = 0; q < 18; ++q){
            int e = t + q * 512;
            int co  = e / 288;
            int rem = e - co * 288;
            int ci  = rem / 9;
            int tap = rem - ci * 9;
            w2f16[(tap * 32 + co) * 32 + (ci ^ SWZ(co))] = f2h_bits(w2[e]);
        }
        return;
    }

    // ---------------- cveck role ----------------
    float* ws_l = reinterpret_cast<float*>(smem);
    float* ws_r = reinterpret_cast<float*>(smem + 4096);
    float* red  = reinterpret_cast<float*>(smem + 8192);
    float* cvs  = reinterpret_cast<float*>(smem + 10240);
    float* w1s  = reinterpret_cast<float*>(smem + 10368);

    #pragma unroll
    for (int q = 0; q < 5; ++q){
        int i4 = t + q * 512;
        if (i4 < 2304)
            *reinterpret_cast<float4*>(&w1s[i4 * 4]) =
                *reinterpret_cast<const float4*>(w1 + i4 * 4);
    }
    for (int j = t; j < 1024; j += 512){
        float sl = 0.f, sr = 0.f;
        #pragma unroll
        for (int b = 0; b < 16; ++b){
            sl += part[b * 1024 + j];
            sr += part[16384 + b * 1024 + j];
        }
        ws_l[j] = sl; ws_r[j] = sr;
    }
    __syncthreads();
    {
        const int h = t & 31;
        const int seg = t >> 5;
        const float* wl = W_hopi + (size_t)h * 2048 + seg * 64;
        const float* wr = wl + 1024;
        float s = 0.f;
        #pragma unroll 8
        for (int j = 0; j < 64; j += 4){
            float4 a = *reinterpret_cast<const float4*>(wl + j);
            float4 b = *reinterpret_cast<const float4*>(wr + j);
            const float* l = &ws_l[seg * 64 + j];
            const float* r = &ws_r[seg * 64 + j];
            s = fmaf(l[0], a.x, s); s = fmaf(l[1], a.y, s);
            s = fmaf(l[2], a.z, s); s = fmaf(l[3], a.w, s);
            s = fmaf(r[0], b.x, s); s = fmaf(r[1], b.y, s);
            s = fmaf(r[2], b.z, s); s = fmaf(r[3], b.w, s);
        }
        red[t] = s;
    }
    __syncthreads();
    if (t < 32){
        float tot = b_hopi[t];
        #pragma unroll
        for (int g = 0; g < 16; ++g) tot += red[g * 32 + t];
        cvs[t] = tot;
    }
    __syncthreads();
    for (int e = t; e < 288; e += 512){
        int co  = e & 31;
        int cse = e >> 5;
        int yc  = cse / 3, xc = cse - yc * 3;
        float sum = b1[co];
        for (int ci = 0; ci < 32; ++ci){
            const float* wp = &w1s[co * 288 + ci * 9];
            float t00 = wp[0], t01 = wp[1], t02 = wp[2];
            float t10 = wp[3], t11 = wp[4], t12 = wp[5];
            float t20 = wp[6], t21 = wp[7], t22 = wp[8];
            float r0, r1, r2;
            if (xc == 0){ r0 = t00+t01+t02; r1 = t10+t11+t12; r2 = t20+t21+t22; }
            else if (xc == 1){ r0 = t01+t02; r1 = t11+t12; r2 = t21+t22; }
            else { r0 = t00+t01; r1 = t10+t11; r2 = t20+t21; }
            float wsum = (yc == 0) ? (r0+r1+r2) : ((yc == 1) ? (r1+r2) : (r0+r1));
            sum = fmaf(cvs[ci], wsum, sum);
        }
        Kp[cse * 32 + co] = sum;
    }
}

// ---------------------------------------------------------------------------
// K3: persistent conv. grid 512 x 512 thr; each block = 8 tiles of one row.
// ys double-buffered (2x20736 B) + wB (18432 B) = 59,904 B LDS.
// Bf hoisted to VGPRs once per block; u-octs shared across tiles; v-octs
// prefetched under the MFMA phase; one barrier per tile.
// ---------------------------------------------------------------------------
__global__ __launch_bounds__(512) void conv_kernel(
    const short* __restrict__ U16, const short* __restrict__ V16,
    const float* __restrict__ Kp, const short* __restrict__ w2f16,
    const float* __restrict__ b2,
    const float* __restrict__ w3, const float* __restrict__ b3,
    float* __restrict__ outp)
{
    __shared__ __attribute__((aligned(16))) short ysbuf[2][18 * 18 * 32];
    __shared__ __attribute__((aligned(16))) short wB[9 * 32 * 32];

    const int t    = threadIdx.x;
    const int wid  = t >> 6;
    const int lane = t & 63;
    const int lr   = lane & 15;
    const int lg   = lane >> 4;

    const int ty  = blockIdx.x >> 3;         // 0..63
    const int oy0 = ty * 16;
    const int tx0 = (blockIdx.x & 7) * 8;    // first of 8 tiles in this row
    const bool rowInt = (ty >= 1) && (ty <= 62);

    // ---- stage wB (uint4 copy of prepacked w2f16) ----
    {
        const uint4* src = reinterpret_cast<const uint4*>(w2f16);
        uint4* dst = reinterpret_cast<uint4*>(wB);
        #pragma unroll
        for (int e = t; e < 1152; e += 512)
            dst[e] = src[e];
    }

    // ---- per-thread staging geometry: 1296 octs over 3 passes ----
    const int c8 = (t & 3) * 8;
    int poA[3], ryoA[3], rxoA[3];
    bool act[3];
    #pragma unroll
    for (int p = 0; p < 3; ++p){
        int idx = t + p * 512;
        act[p] = idx < 1296;
        int po = act[p] ? (idx >> 2) : 0;
        poA[p]  = po;
        ryoA[p] = po / 18;
        rxoA[p] = po - ryoA[p] * 18;
    }

    half8 k00;
    {
        float4 ka = *reinterpret_cast<const float4*>(&Kp[c8]);
        float4 kb = *reinterpret_cast<const float4*>(&Kp[c8 + 4]);
        k00 = pack2(ka, kb);
    }

    // ---- u octs: row-fixed, shared by all 8 tiles ----
    half8 uq[3];
    if (rowInt){
        #pragma unroll
        for (int p = 0; p < 3; ++p)
            if (act[p])
                uq[p] = *reinterpret_cast<const half8*>(
                    &U16[(oy0 - 1 + ryoA[p]) * 32 + c8]);
    }
    // ---- v octs: prefetch tile 0 ----
    half8 vq[3];
    if (rowInt && tx0 >= 1){
        #pragma unroll
        for (int p = 0; p < 3; ++p)
            if (act[p])
                vq[p] = *reinterpret_cast<const half8*>(
                    &V16[(tx0 * 16 - 1 + rxoA[p]) * 32 + c8]);
    }
    __syncthreads();     // wB visible

    // ---- Bf hoisted: 18 LDS reads per lane, held across all tiles ----
    half8 Bf[2][9];
    float bias[2], w3v[2];
    #pragma unroll
    for (int n = 0; n < 2; ++n){
        int co = n * 16 + lr;
        bias[n] = b2[co];
        w3v[n]  = w3[co];
        #pragma unroll
        for (int tap = 0; tap < 9; ++tap)
            Bf[n][tap] = *reinterpret_cast<const half8*>(
                &wB[(tap * 32 + co) * 32 + ((lg * 8) ^ SWZ(co))]);
    }
    const float b3v = b3[0];

    int cur = 0;
    for (int i = 0; i < 8; ++i){
        const int tx  = tx0 + i;
        const int ox0 = tx * 16;
        const bool fast = rowInt && (tx >= 1) && (tx <= 62);
        short* ys = ysbuf[cur];

        // ---- write ys[cur] ----
        if (fast){
            #pragma unroll
            for (int p = 0; p < 3; ++p) if (act[p]){
                half8 r = uq[p] + vq[p] + k00;
                #pragma unroll
                for (int e = 0; e < 8; ++e)
                    r[e] = r[e] > (_Float16)0.f ? r[e] : (_Float16)0.f;
                *reinterpret_cast<half8*>(&ys[poA[p] * 32 + (c8 ^ SWZ(rxoA[p]))]) = r;
            }
        } else {
            #pragma unroll
            for (int p = 0; p < 3; ++p) if (act[p]){
                int gy = oy0 - 1 + ryoA[p];
                int gx = ox0 - 1 + rxoA[p];
                half8 h;
                #pragma unroll
                for (int e = 0; e < 8; ++e) h[e] = (_Float16)0.f;
                if ((unsigned)gy < 1024u && (unsigned)gx < 1024u){
                    int yc = (gy == 0) ? 1 : ((gy == 1023) ? 2 : 0);
                    int xc = (gx == 0) ? 1 : ((gx == 1023) ? 2 : 0);
                    half8 u = *reinterpret_cast<const half8*>(
                        &U16[((size_t)(xc << 10) + gy) * 32 + c8]);
                    half8 v = *reinterpret_cast<const half8*>(
                        &V16[((size_t)(yc << 10) + gx) * 32 + c8]);
                    const float* kp = &Kp[(yc * 3 + xc) * 32 + c8];
                    #pragma unroll
                    for (int e = 0; e < 8; ++e)
                        h[e] = (_Float16)fmaxf((float)u[e] + (float)v[e] + kp[e], 0.f);
                }
                *reinterpret_cast<half8*>(&ys[poA[p] * 32 + (c8 ^ SWZ(rxoA[p]))]) = h;
            }
        }
        __syncthreads();     // ys[cur] ready; also all waves past last tile's MFMA

        // ---- prefetch next tile's v (in flight under MFMA) ----
        if (i < 7){
            const int txn = tx + 1;
            if (rowInt && txn >= 1 && txn <= 62){
                #pragma unroll
                for (int p = 0; p < 3; ++p)
                    if (act[p])
                        vq[p] = *reinterpret_cast<const half8*>(
                            &V16[(txn * 16 - 1 + rxoA[p]) * 32 + c8]);
            }
        }

        // ---- conv2+conv3 MFMA on ys[cur] ----
        for (int s = wid; s < 16; s += 8){
            const int ry = s;
            const int rx = lr;
            f32x4 acc0 = {0.f, 0.f, 0.f, 0.f};
            f32x4 acc1 = {0.f, 0.f, 0.f, 0.f};
            #pragma unroll
            for (int tap = 0; tap < 9; ++tap){
                const int dy = tap / 3, dx = tap - (tap / 3) * 3;
                int pix = (ry + dy) * 18 + rx + dx;
                half8 A = *reinterpret_cast<const half8*>(
                    &ys[pix * 32 + ((lg * 8) ^ SWZ(rx + dx))]);
                acc0 = __builtin_amdgcn_mfma_f32_16x16x32_f16(A, Bf[0][tap], acc0, 0, 0, 0);
                acc1 = __builtin_amdgcn_mfma_f32_16x16x32_f16(A, Bf[1][tap], acc1, 0, 0, 0);
            }
            float part[4];
            #pragma unroll
            for (int j = 0; j < 4; ++j)
                part[j] = w3v[0] * fmaxf(acc0[j] + bias[0], 0.f)
                        + w3v[1] * fmaxf(acc1[j] + bias[1], 0.f);
            #pragma unroll
            for (int m = 1; m < 16; m <<= 1)
                #pragma unroll
                for (int j = 0; j < 4; ++j)
                    part[j] += __shfl_xor(part[j], m);
            if (lr == 0){
                float4 o = make_float4(part[0] + b3v, part[1] + b3v,
                                       part[2] + b3v, part[3] + b3v);
                *reinterpret_cast<float4*>(outp + (size_t)(oy0 + s) * 1024 + ox0 + lg * 4) = o;
            }
        }
        cur ^= 1;
    }
}

// ---------------------------------------------------------------------------
extern "C" void kernel_launch(void* const* d_in, const int* in_sizes, int n_in,
                              void* d_out, int out_size, void* d_ws, size_t ws_size,
                              hipStream_t stream)
{
    const float* lig_nf = (const float*)d_in[0];
    const float* lig_ef = (const float*)d_in[1];
    const float* rec_nf = (const float*)d_in[3];
    const float* rec_ef = (const float*)d_in[4];
    const float* Wn     = (const float*)d_in[6];
    const float* bn     = (const float*)d_in[7];
    const float* We     = (const float*)d_in[8];
    const float* be     = (const float*)d_in[9];
    const float* W_hopi = (const float*)d_in[12];
    const float* b_hopi = (const float*)d_in[13];
    const float* w1     = (const float*)d_in[14];
    const float* b1     = (const float*)d_in[15];
    const float* w2     = (const float*)d_in[16];
    const float* b2     = (const float*)d_in[17];
    const float* w3     = (const float*)d_in[18];
    const float* b3     = (const float*)d_in[19];
    float* outp = (float*)d_out;

    float* part  = (float*)d_ws;                              // [2][16][1024] f32
    float* Kp    = (float*)((char*)d_ws + 393216);            // 3*3*32 f32
    short* U16   = (short*)((char*)d_ws + 394368);            // 3*1024*32 f16
    short* V16   = (short*)((char*)d_ws + 590976);            // 3*1024*32 f16
    short* w2f16 = (short*)((char*)d_ws + 787584);            // 9216 f16 swizzled

    dim3 g1(8, 16, 2);
    gnn_kernel<<<g1, 512, 0, stream>>>(lig_nf, lig_ef, rec_nf, rec_ef,
                                       Wn, We, bn, be, part);
    pp_kernel<<<34, 512, 0, stream>>>(lig_nf, rec_nf, W_hopi, b_hopi,
                                      w1, b1, w2, part, Kp, U16, V16, w2f16);
    conv_kernel<<<512, 512, 0, stream>>>(U16, V16, Kp, w2f16, b2, w3, b3, outp);
}

// Round 18
// 113.957 us; speedup vs baseline: 1.0253x; 1.0253x over previous
//
#include <hip/hip_runtime.h>

// All tensors float32. Math structure exploited:
//  - softmax over axis of size 1 == 1.0 -> attn all-ones, Wa/ba dead.
//  - weighted = row-sum of tanh(agg), broadcast over COLUMNS (N==D quirk).
//  - lig_p = nf@Wl.T + const  ->  x0[h,i,j] = PL[i,h] + PR[j,h] + c[h]
//  - conv1 is LINEAR in rank-structured x0: y1_pre = U[xc][y] + V[yc][x] + K'.
//  - ROUND-18: pp's Ws staging had the round-9 disease (runtime loop bounds +
//    int divides -> serial scattered w1 loads at the head of a 34-block
//    kernel whose wall time IS single-block serial time). Ws now computed
//    AFTER the P-GEMM from 9 contiguous scalar tap loads per (co,ci) pair
//    (independent, register sums, no divides). conv reverted to round-16
//    version (46.0us measured best; r17 persistent variant was 48).

typedef _Float16 half8 __attribute__((ext_vector_type(8)));
typedef _Float16 half4 __attribute__((ext_vector_type(4)));
typedef float    f32x4 __attribute__((ext_vector_type(4)));

__device__ __forceinline__ short f2h_bits(float f){
    _Float16 h = (_Float16)f;          // RNE
    return __builtin_bit_cast(short, h);
}
__device__ __forceinline__ half8 pack2(const float4& x, const float4& y){
    half8 r;
    r[0] = (_Float16)x.x; r[1] = (_Float16)x.y;
    r[2] = (_Float16)x.z; r[3] = (_Float16)x.w;
    r[4] = (_Float16)y.x; r[5] = (_Float16)y.y;
    r[6] = (_Float16)y.z; r[7] = (_Float16)y.w;
    return r;
}
__device__ __forceinline__ half4 pack4(const float4& x){
    half4 r;
    r[0] = (_Float16)x.x; r[1] = (_Float16)x.y;
    r[2] = (_Float16)x.z; r[3] = (_Float16)x.w;
    return r;
}
__device__ __forceinline__ float tanh_fast(float x){
    float e = __expf(2.f * x);
    return 1.f - 2.f / (e + 1.f);
}

// ci-block swizzle for conv LDS tiles (round-4 verified layout)
#define SWZ(c) ((((c) >> 1) & 3) << 3)

// ---------------------------------------------------------------------------
// K1 (MFMA): gnn, BM=128/BN=64/BK=64, 512 thr, depth-2 reg prefetch.
// grid (8,16,2). (round-15..17 verbatim)
// ---------------------------------------------------------------------------
#define GNN_LOAD(AV, BV, KBN) {                                              \
    const int kbn_ = (KBN) & 2047;                                           \
    const float* Asrc_ = (kbn_ < 1024) ? A0 : A1;                            \
    const float* Bsrc_ = (kbn_ < 1024) ? Wn : We;                            \
    const int kk_ = kbn_ & 1023;                                             \
    const float* ap_ = Asrc_ + (size_t)(j0 + arow) * 1024 + kk_ + akc;       \
    const float* bp_ = Bsrc_ + (size_t)(d0 + brow) * 1024 + kk_ + bkc;       \
    AV[0] = *reinterpret_cast<const float4*>(ap_);                           \
    AV[1] = *reinterpret_cast<const float4*>(ap_ + 4);                       \
    AV[2] = *reinterpret_cast<const float4*>(ap_ + 8);                       \
    AV[3] = *reinterpret_cast<const float4*>(ap_ + 12);                      \
    BV[0] = *reinterpret_cast<const float4*>(bp_);                           \
    BV[1] = *reinterpret_cast<const float4*>(bp_ + 4);                       \
}

#define GNN_STAGE(AV, BV) {                                                  \
    const int ga_ = (t & 3) * 2;                                             \
    const int sa_ = arow & 7;                                                \
    *reinterpret_cast<half8*>(&As[arow * 64 + ((ga_    ) ^ sa_) * 8]) = pack2(AV[0], AV[1]); \
    *reinterpret_cast<half8*>(&As[arow * 64 + ((ga_ + 1) ^ sa_) * 8]) = pack2(AV[2], AV[3]); \
    *reinterpret_cast<half8*>(&Bs[brow * 64 + ((t & 7) ^ (brow & 7)) * 8]) = pack2(BV[0], BV[1]); \
}

#define GNN_MFMA() {                                                         \
    _Pragma("unroll")                                                        \
    for (int ks = 0; ks < 2; ++ks){                                          \
        half8 Af[2], Bf[2];                                                  \
        _Pragma("unroll")                                                    \
        for (int m = 0; m < 2; ++m){                                         \
            int row = wm * 32 + m * 16 + lr;                                 \
            int g   = ((ks * 4 + lg) ^ (row & 7)) * 8;                       \
            Af[m] = *reinterpret_cast<const half8*>(&As[row * 64 + g]);      \
        }                                                                    \
        _Pragma("unroll")                                                    \
        for (int n = 0; n < 2; ++n){                                         \
            int col = wn * 32 + n * 16 + lr;                                 \
            int g   = ((ks * 4 + lg) ^ (col & 7)) * 8;                       \
            Bf[n] = *reinterpret_cast<const half8*>(&Bs[col * 64 + g]);      \
        }                                                                    \
        _Pragma("unroll")                                                    \
        for (int m = 0; m < 2; ++m)                                          \
            _Pragma("unroll")                                                \
            for (int n = 0; n < 2; ++n)                                      \
                acc[m][n] = __builtin_amdgcn_mfma_f32_16x16x32_f16(          \
                    Af[m], Bf[n], acc[m][n], 0, 0, 0);                       \
    }                                                                        \
}

__global__ __launch_bounds__(512) void gnn_kernel(
    const float* __restrict__ lig_nf, const float* __restrict__ lig_ef,
    const float* __restrict__ rec_nf, const float* __restrict__ rec_ef,
    const float* __restrict__ Wn, const float* __restrict__ We,
    const float* __restrict__ bn, const float* __restrict__ be,
    float* __restrict__ part)   // [2][16][1024]
{
    __shared__ __attribute__((aligned(16))) short As[128 * 64];
    __shared__ __attribute__((aligned(16))) short Bs[64 * 64];
    __shared__ float red[128][2];

    const int t  = threadIdx.x;
    const int cx = blockIdx.z;
    const float* A0 = cx ? rec_nf : lig_nf;
    const float* A1 = cx ? rec_ef : lig_ef;
    const int j0 = blockIdx.x * 128;
    const int d0 = blockIdx.y * 64;

    const int wid  = t >> 6;
    const int wm   = wid >> 1;
    const int wn   = wid & 1;
    const int lane = t & 63;
    const int lr   = lane & 15;
    const int lg   = lane >> 4;

    f32x4 acc[2][2];
    #pragma unroll
    for (int m = 0; m < 2; ++m)
        #pragma unroll
        for (int n = 0; n < 2; ++n)
            acc[m][n] = (f32x4){0.f, 0.f, 0.f, 0.f};

    const int arow = t >> 2;
    const int akc  = (t & 3) * 16;
    const int brow = t >> 3;
    const int bkc  = (t & 7) * 8;

    float4 avA[4], bvA[2], avB[4], bvB[2];
    GNN_LOAD(avA, bvA, 0);
    GNN_LOAD(avB, bvB, 64);

    for (int kb = 0; kb < 2048; kb += 128){
        __syncthreads();
        GNN_STAGE(avA, bvA);
        GNN_LOAD(avA, bvA, kb + 128);
        __syncthreads();
        GNN_MFMA();
        __syncthreads();
        GNN_STAGE(avB, bvB);
        GNN_LOAD(avB, bvB, kb + 192);
        __syncthreads();
        GNN_MFMA();
    }

    float rowsum[2][4];
    #pragma unroll
    for (int m = 0; m < 2; ++m)
        #pragma unroll
        for (int jj = 0; jj < 4; ++jj) rowsum[m][jj] = 0.f;
    #pragma unroll
    for (int n = 0; n < 2; ++n){
        int d = d0 + wn * 32 + n * 16 + lr;
        float bias = bn[d] + be[d];
        #pragma unroll
        for (int m = 0; m < 2; ++m)
            #pragma unroll
            for (int jj = 0; jj < 4; ++jj)
                rowsum[m][jj] += tanh_fast(acc[m][n][jj] + bias);
    }
    #pragma unroll
    for (int mask = 1; mask < 16; mask <<= 1)
        #pragma unroll
        for (int m = 0; m < 2; ++m)
            #pragma unroll
            for (int jj = 0; jj < 4; ++jj)
                rowsum[m][jj] += __shfl_xor(rowsum[m][jj], mask);
    __syncthreads();
    if (lr == 0){
        #pragma unroll
        for (int m = 0; m < 2; ++m)
            #pragma unroll
            for (int jj = 0; jj < 4; ++jj)
                red[wm * 32 + m * 16 + lg * 4 + jj][wn] = rowsum[m][jj];
    }
    __syncthreads();
    if (t < 128)
        part[(size_t)cx * 16384 + (size_t)blockIdx.y * 1024 + j0 + t]
            = red[t][0] + red[t][1];
}

// ---------------------------------------------------------------------------
// K2: pp_kernel. grid 34 x 512 thr.
//  roles 0..31: P GEMM (80-row A-tile incl. halo, BK=64, depth-2 prefetch),
//               THEN Ws from contiguous tap loads (round-18 fix), then uv.
//  role 32: cveck -> Kp ; role 33: w2pack -> w2f16
// ---------------------------------------------------------------------------
#define PP_LOAD(AV, BV, KBN) {                                               \
    const int kcol_ = (KBN) & 1023;                                          \
    _Pragma("unroll")                                                        \
    for (int p = 0; p < 3; ++p){                                             \
        int e_ = t + 512 * p;                                                \
        if (e_ < 1280){                                                      \
            int rowl_ = e_ >> 4;                                             \
            int grow_ = r0 - 8 + rowl_;                                      \
            if ((unsigned)grow_ < 1024u)                                     \
                AV[p] = *reinterpret_cast<const float4*>(                    \
                    nf + (size_t)grow_ * 1024 + kcol_ + (e_ & 15) * 4);      \
            else                                                             \
                AV[p] = make_float4(0.f, 0.f, 0.f, 0.f);                     \
        }                                                                    \
    }                                                                        \
    BV = *reinterpret_cast<const float4*>(                                   \
        W + (size_t)(t >> 4) * 2048 + kcol_ + (t & 15) * 4);                 \
}

#define PP_STAGE(AV, BV) {                                                   \
    _Pragma("unroll")                                                        \
    for (int p = 0; p < 3; ++p){                                             \
        int e_ = t + 512 * p;                                                \
        if (e_ < 1280){                                                      \
            int rowl_ = e_ >> 4;                                             \
            int ga_ = (e_ & 15) >> 1;                                        \
            int sub_ = (e_ & 1) * 4;                                         \
            *reinterpret_cast<half4*>(                                       \
                &As[rowl_ * 64 + ((ga_ ^ (rowl_ & 7)) * 8) + sub_]) = pack4(AV[p]); \
        }                                                                    \
    }                                                                        \
    {                                                                        \
        int row_ = t >> 4;                                                   \
        int ga_ = (t & 15) >> 1;                                             \
        int sub_ = (t & 1) * 4;                                              \
        *reinterpret_cast<half4*>(                                           \
            &Bs[row_ * 64 + ((ga_ ^ (row_ & 7)) * 8) + sub_]) = pack4(BV);   \
    }                                                                        \
}

#define PP_MFMA() {                                                          \
    if (wid < 5){                                                            \
        _Pragma("unroll")                                                    \
        for (int ks = 0; ks < 2; ++ks){                                      \
            int ar_ = wid * 16 + lr;                                         \
            half8 Af = *reinterpret_cast<const half8*>(                      \
                &As[ar_ * 64 + ((ks * 4 + lg) ^ (ar_ & 7)) * 8]);            \
            _Pragma("unroll")                                                \
            for (int n = 0; n < 2; ++n){                                     \
                int col_ = n * 16 + lr;                                      \
                half8 Bf = *reinterpret_cast<const half8*>(                  \
                    &Bs[col_ * 64 + ((ks * 4 + lg) ^ (col_ & 7)) * 8]);      \
                pacc[n] = __builtin_amdgcn_mfma_f32_16x16x32_f16(            \
                    Af, Bf, pacc[n], 0, 0, 0);                               \
            }                                                                \
        }                                                                    \
    }                                                                        \
}

__global__ __launch_bounds__(512) void pp_kernel(
    const float* __restrict__ lig_nf, const float* __restrict__ rec_nf,
    const float* __restrict__ W_hopi, const float* __restrict__ b_hopi,
    const float* __restrict__ w1, const float* __restrict__ b1,
    const float* __restrict__ w2,
    const float* __restrict__ part,
    float* __restrict__ Kp, short* __restrict__ U16, short* __restrict__ V16,
    short* __restrict__ w2f16)
{
    __shared__ __attribute__((aligned(16))) char smem[47232];
    const int t = threadIdx.x;
    const int role = blockIdx.x;

    if (role < 32){
        short* As = reinterpret_cast<short*>(smem);            // 80x64  @0
        short* Bs = reinterpret_cast<short*>(smem + 10240);    // 32x64
        short* Pz = reinterpret_cast<short*>(smem + 14336);    // 80 x stride40
        short* Ws = reinterpret_cast<short*>(smem + 20736);    // 3x32 x stride104

        const int cx = role >> 4;
        const int r0 = (role & 15) * 64;
        const float* nf = cx ? rec_nf : lig_nf;
        const float* W  = W_hopi + (cx ? 1024 : 0);
        short* O = cx ? V16 : U16;

        const int wid = t >> 6;
        const int lane = t & 63;
        const int lr = lane & 15;
        const int lg = lane >> 4;

        // ---- P GEMM: 80 rows x 32 h, K=1024, depth-2 prefetch ----
        f32x4 pacc[2];
        pacc[0] = (f32x4){0.f, 0.f, 0.f, 0.f};
        pacc[1] = (f32x4){0.f, 0.f, 0.f, 0.f};

        float4 avA[3], avB[3];
        float4 bvA, bvB;
        PP_LOAD(avA, bvA, 0);
        PP_LOAD(avB, bvB, 64);

        for (int kb = 0; kb < 1024; kb += 128){
            __syncthreads();
            PP_STAGE(avA, bvA);
            PP_LOAD(avA, bvA, kb + 128);
            __syncthreads();
            PP_MFMA();
            __syncthreads();
            PP_STAGE(avB, bvB);
            PP_LOAD(avB, bvB, kb + 192);
            __syncthreads();
            PP_MFMA();
        }

        // ---- write P (f16) to Pz (stride 40) ----
        if (wid < 5){
            #pragma unroll
            for (int n = 0; n < 2; ++n)
                #pragma unroll
                for (int jj = 0; jj < 4; ++jj){
                    int rowl = wid * 16 + lg * 4 + jj;
                    Pz[rowl * 40 + n * 16 + lr] = f2h_bits(pacc[n][jj]);
                }
        }

        // ---- Ws from contiguous tap loads (no divides, no runtime bounds) ----
        #pragma unroll
        for (int q = 0; q < 2; ++q){
            int pr = t * 2 + q;              // (co,ci) pair 0..1023
            int co = pr >> 5;
            int ci = pr & 31;
            const float* wp = w1 + co * 288 + ci * 9;
            float tap[9];
            #pragma unroll
            for (int e = 0; e < 9; ++e) tap[e] = wp[e];
            #pragma unroll
            for (int d = 0; d < 3; ++d){
                float ta, tb, tc;
                if (cx == 0){ ta = tap[d * 3 + 0]; tb = tap[d * 3 + 1]; tc = tap[d * 3 + 2]; }
                else        { ta = tap[0 + d];     tb = tap[3 + d];     tc = tap[6 + d]; }
                Ws[(0 * 32 + co) * 104 + d * 32 + ci] = f2h_bits(ta + tb + tc);
                Ws[(1 * 32 + co) * 104 + d * 32 + ci] = f2h_bits(tb + tc);
                Ws[(2 * 32 + co) * 104 + d * 32 + ci] = f2h_bits(ta + tb);
            }
        }
        __syncthreads();

        // ---- uv GEMM (waves 0-3): 64 rows x 32 co x K=96 ----
        if (wid < 4){
            f32x4 uacc[3][2];
            #pragma unroll
            for (int cs = 0; cs < 3; ++cs)
                #pragma unroll
                for (int n = 0; n < 2; ++n)
                    uacc[cs][n] = (f32x4){0.f, 0.f, 0.f, 0.f};
            #pragma unroll
            for (int d = 0; d < 3; ++d){
                int ar = wid * 16 + lr;
                half8 Ap = *reinterpret_cast<const half8*>(
                    &Pz[(7 + ar + d) * 40 + lg * 8]);
                #pragma unroll
                for (int cs = 0; cs < 3; ++cs)
                    #pragma unroll
                    for (int n = 0; n < 2; ++n){
                        half8 Bp = *reinterpret_cast<const half8*>(
                            &Ws[(cs * 32 + n * 16 + lr) * 104 + d * 32 + lg * 8]);
                        uacc[cs][n] = __builtin_amdgcn_mfma_f32_16x16x32_f16(
                            Ap, Bp, uacc[cs][n], 0, 0, 0);
                    }
            }
            #pragma unroll
            for (int cs = 0; cs < 3; ++cs)
                #pragma unroll
                for (int n = 0; n < 2; ++n)
                    #pragma unroll
                    for (int jj = 0; jj < 4; ++jj){
                        int grow = r0 + wid * 16 + lg * 4 + jj;
                        O[((size_t)(cs << 10) + grow) * 32 + n * 16 + lr]
                            = f2h_bits(uacc[cs][n][jj]);
                    }
        }
        return;
    }

    if (role == 33){
        #pragma unroll
        for (int q = 0; q < 18; ++q){
            int e = t + q * 512;
            int co  = e / 288;
            int rem = e - co * 288;
            int ci  = rem / 9;
            int tap = rem - ci * 9;
            w2f16[(tap * 32 + co) * 32 + (ci ^ SWZ(co))] = f2h_bits(w2[e]);
        }
        return;
    }

    // ---------------- cveck role ----------------
    float* ws_l = reinterpret_cast<float*>(smem);
    float* ws_r = reinterpret_cast<float*>(smem + 4096);
    float* red  = reinterpret_cast<float*>(smem + 8192);
    float* cvs  = reinterpret_cast<float*>(smem + 10240);
    float* w1s  = reinterpret_cast<float*>(smem + 10368);

    #pragma unroll
    for (int q = 0; q < 5; ++q){
        int i4 = t + q * 512;
        if (i4 < 2304)
            *reinterpret_cast<float4*>(&w1s[i4 * 4]) =
                *reinterpret_cast<const float4*>(w1 + i4 * 4);
    }
    for (int j = t; j < 1024; j += 512){
        float sl = 0.f, sr = 0.f;
        #pragma unroll
        for (int b = 0; b < 16; ++b){
            sl += part[b * 1024 + j];
            sr += part[16384 + b * 1024 + j];
        }
        ws_l[j] = sl; ws_r[j] = sr;
    }
    __syncthreads();
    {
        const int h = t & 31;
        const int seg = t >> 5;
        const float* wl = W_hopi + (size_t)h * 2048 + seg * 64;
        const float* wr = wl + 1024;
        float s = 0.f;
        #pragma unroll 8
        for (int j = 0; j < 64; j += 4){
            float4 a = *reinterpret_cast<const float4*>(wl + j);
            float4 b = *reinterpret_cast<const float4*>(wr + j);
            const float* l = &ws_l[seg * 64 + j];
            const float* r = &ws_r[seg * 64 + j];
            s = fmaf(l[0], a.x, s); s = fmaf(l[1], a.y, s);
            s = fmaf(l[2], a.z, s); s = fmaf(l[3], a.w, s);
            s = fmaf(r[0], b.x, s); s = fmaf(r[1], b.y, s);
            s = fmaf(r[2], b.z, s); s = fmaf(r[3], b.w, s);
        }
        red[t] = s;
    }
    __syncthreads();
    if (t < 32){
        float tot = b_hopi[t];
        #pragma unroll
        for (int g = 0; g < 16; ++g) tot += red[g * 32 + t];
        cvs[t] = tot;
    }
    __syncthreads();
    for (int e = t; e < 288; e += 512){
        int co  = e & 31;
        int cse = e >> 5;
        int yc  = cse / 3, xc = cse - yc * 3;
        float sum = b1[co];
        for (int ci = 0; ci < 32; ++ci){
            const float* wp = &w1s[co * 288 + ci * 9];
            float t00 = wp[0], t01 = wp[1], t02 = wp[2];
            float t10 = wp[3], t11 = wp[4], t12 = wp[5];
            float t20 = wp[6], t21 = wp[7], t22 = wp[8];
            float r0, r1, r2;
            if (xc == 0){ r0 = t00+t01+t02; r1 = t10+t11+t12; r2 = t20+t21+t22; }
            else if (xc == 1){ r0 = t01+t02; r1 = t11+t12; r2 = t21+t22; }
            else { r0 = t00+t01; r1 = t10+t11; r2 = t20+t21; }
            float wsum = (yc == 0) ? (r0+r1+r2) : ((yc == 1) ? (r1+r2) : (r0+r1));
            sum = fmaf(cvs[ci], wsum, sum);
        }
        Kp[cse * 32 + co] = sum;
    }
}

// ---------------------------------------------------------------------------
// K3: stage ys = relu(U+V+K') (interior fast path in packed f16), wB by uint4
// copy of prepacked w2f16, then conv2+relu+conv3 on f16 MFMA. LDS = 39,168 B.
// block 512, grid 64x64. (round-16 verbatim -- best measured conv, 46.0us)
// ---------------------------------------------------------------------------
__global__ __launch_bounds__(512) void conv_kernel(
    const short* __restrict__ U16, const short* __restrict__ V16,
    const float* __restrict__ Kp, const short* __restrict__ w2f16,
    const float* __restrict__ b2,
    const float* __restrict__ w3, const float* __restrict__ b3,
    float* __restrict__ outp)
{
    __shared__ __attribute__((aligned(16))) short ys[18 * 18 * 32];
    __shared__ __attribute__((aligned(16))) short wB[9 * 32 * 32];

    const int t    = threadIdx.x;
    const int oy0  = blockIdx.y * 16;
    const int ox0  = blockIdx.x * 16;
    const int wid  = t >> 6;
    const int lane = t & 63;
    const int lr   = lane & 15;
    const int lg   = lane >> 4;

    {
        const uint4* src = reinterpret_cast<const uint4*>(w2f16);
        uint4* dst = reinterpret_cast<uint4*>(wB);
        #pragma unroll
        for (int e = t; e < 1152; e += 512)
            dst[e] = src[e];
    }
    const bool interior = (blockIdx.x >= 1) & (blockIdx.x <= 62) &
                          (blockIdx.y >= 1) & (blockIdx.y <= 62);
    if (interior){
        const int cp = (t & 7) * 4;
        half4 k00;
        {
            float4 kf = *reinterpret_cast<const float4*>(&Kp[cp]);
            k00[0] = (_Float16)kf.x; k00[1] = (_Float16)kf.y;
            k00[2] = (_Float16)kf.z; k00[3] = (_Float16)kf.w;
        }
        #pragma unroll
        for (int pass = 0; pass < 6; ++pass){
            int idx = t + pass * 512;
            if (idx < 2592){
                int po  = idx >> 3;
                int ryo = po / 18;
                int rxo = po - ryo * 18;
                int gy = oy0 - 1 + ryo, gx = ox0 - 1 + rxo;
                half4 u = *reinterpret_cast<const half4*>(&U16[gy * 32 + cp]);
                half4 v = *reinterpret_cast<const half4*>(&V16[gx * 32 + cp]);
                half4 r = u + v + k00;
                #pragma unroll
                for (int e = 0; e < 4; ++e)
                    r[e] = r[e] > (_Float16)0.f ? r[e] : (_Float16)0.f;
                *reinterpret_cast<half4*>(&ys[po * 32 + (cp ^ SWZ(rxo))]) = r;
            }
        }
    } else {
        #pragma unroll
        for (int pass = 0; pass < 6; ++pass){
            int idx = t + pass * 512;
            if (idx < 2592){
                int po  = idx >> 3;
                int cp  = (idx & 7) * 4;
                int ryo = po / 18;
                int rxo = po - ryo * 18;
                int gy = oy0 - 1 + ryo, gx = ox0 - 1 + rxo;
                half4 h = {(_Float16)0.f, (_Float16)0.f, (_Float16)0.f, (_Float16)0.f};
                if ((unsigned)gy < 1024u && (unsigned)gx < 1024u){
                    int yc = (gy == 0) ? 1 : ((gy == 1023) ? 2 : 0);
                    int xc = (gx == 0) ? 1 : ((gx == 1023) ? 2 : 0);
                    half4 u = *reinterpret_cast<const half4*>(
                        &U16[((size_t)(xc << 10) + gy) * 32 + cp]);
                    half4 v = *reinterpret_cast<const half4*>(
                        &V16[((size_t)(yc << 10) + gx) * 32 + cp]);
                    float4 k = *reinterpret_cast<const float4*>(&Kp[(yc * 3 + xc) * 32 + cp]);
                    h[0] = (_Float16)fmaxf((float)u[0] + (float)v[0] + k.x, 0.f);
                    h[1] = (_Float16)fmaxf((float)u[1] + (float)v[1] + k.y, 0.f);
                    h[2] = (_Float16)fmaxf((float)u[2] + (float)v[2] + k.z, 0.f);
                    h[3] = (_Float16)fmaxf((float)u[3] + (float)v[3] + k.w, 0.f);
                }
                *reinterpret_cast<half4*>(&ys[po * 32 + (cp ^ SWZ(rxo))]) = h;
            }
        }
    }
    __syncthreads();

    {
        half8 Bf[2][9];
        float bias[2], w3v[2];
        #pragma unroll
        for (int n = 0; n < 2; ++n){
            int co = n * 16 + lr;
            bias[n] = b2[co];
            w3v[n]  = w3[co];
            #pragma unroll
            for (int tap = 0; tap < 9; ++tap)
                Bf[n][tap] = *reinterpret_cast<const half8*>(
                    &wB[(tap * 32 + co) * 32 + ((lg * 8) ^ SWZ(co))]);
        }
        const float b3v = b3[0];
        for (int s = wid; s < 16; s += 8){
            int p  = s * 16 + lr;
            int ry = p >> 4;
            int rx = p & 15;
            f32x4 acc0 = {0.f, 0.f, 0.f, 0.f};
            f32x4 acc1 = {0.f, 0.f, 0.f, 0.f};
            #pragma unroll
            for (int tap = 0; tap < 9; ++tap){
                const int dy = tap / 3, dx = tap - (tap / 3) * 3;
                int pix = (ry + dy) * 18 + rx + dx;
                half8 A = *reinterpret_cast<const half8*>(
                    &ys[pix * 32 + ((lg * 8) ^ SWZ(rx + dx))]);
                acc0 = __builtin_amdgcn_mfma_f32_16x16x32_f16(A, Bf[0][tap], acc0, 0, 0, 0);
                acc1 = __builtin_amdgcn_mfma_f32_16x16x32_f16(A, Bf[1][tap], acc1, 0, 0, 0);
            }
            float part[4];
            #pragma unroll
            for (int j = 0; j < 4; ++j)
                part[j] = w3v[0] * fmaxf(acc0[j] + bias[0], 0.f)
                        + w3v[1] * fmaxf(acc1[j] + bias[1], 0.f);
            #pragma unroll
            for (int m = 1; m < 16; m <<= 1)
                #pragma unroll
                for (int j = 0; j < 4; ++j)
                    part[j] += __shfl_xor(part[j], m);
            if (lr == 0){
                float4 o = make_float4(part[0] + b3v, part[1] + b3v,
                                       part[2] + b3v, part[3] + b3v);
                *reinterpret_cast<float4*>(outp + (size_t)(oy0 + s) * 1024 + ox0 + lg * 4) = o;
            }
        }
    }
}

// ---------------------------------------------------------------------------
extern "C" void kernel_launch(void* const* d_in, const int* in_sizes, int n_in,
                              void* d_out, int out_size, void* d_ws, size_t ws_size,
                              hipStream_t stream)
{
    const float* lig_nf = (const float*)d_in[0];
    const float* lig_ef = (const float*)d_in[1];
    const float* rec_nf = (const float*)d_in[3];
    const float* rec_ef = (const float*)d_in[4];
    const float* Wn     = (const float*)d_in[6];
    const float* bn     = (const float*)d_in[7];
    const float* We     = (const float*)d_in[8];
    const float* be     = (const float*)d_in[9];
    const float* W_hopi = (const float*)d_in[12];
    const float* b_hopi = (const float*)d_in[13];
    const float* w1     = (const float*)d_in[14];
    const float* b1     = (const float*)d_in[15];
    const float* w2     = (const float*)d_in[16];
    const float* b2     = (const float*)d_in[17];
    const float* w3     = (const float*)d_in[18];
    const float* b3     = (const float*)d_in[19];
    float* outp = (float*)d_out;

    float* part  = (float*)d_ws;                              // [2][16][1024] f32
    float* Kp    = (float*)((char*)d_ws + 393216);            // 3*3*32 f32
    short* U16   = (short*)((char*)d_ws + 394368);            // 3*1024*32 f16
    short* V16   = (short*)((char*)d_ws + 590976);            // 3*1024*32 f16
    short* w2f16 = (short*)((char*)d_ws + 787584);            // 9216 f16 swizzled

    dim3 g1(8, 16, 2);
    gnn_kernel<<<g1, 512, 0, stream>>>(lig_nf, lig_ef, rec_nf, rec_ef,
                                       Wn, We, bn, be, part);
    pp_kernel<<<34, 512, 0, stream>>>(lig_nf, rec_nf, W_hopi, b_hopi,
                                      w1, b1, w2, part, Kp, U16, V16, w2f16);
    dim3 g3(64, 64);
    conv_kernel<<<g3, 512, 0, stream>>>(U16, V16, Kp, w2f16, b2, w3, b3, outp);
}